// Round 8
// baseline (420.417 us; speedup 1.0000x reference)
//
#include <hip/hip_runtime.h>
#include <hip/hip_bf16.h>

// EdgeBlock fused MLP:
//   out = relu(concat(edge, node[recv], node[send], g) @ W1 + b1) @ W2 + b2
// E=640000, N=10000, D=128, H=256, O=128.
//
// R8: persistent 256 blocks x 512 thr (8 waves, 2M x 4N), 40 tiles/block.
//  - W1/W2 MFMA fragments held in 128 VGPRs for the whole kernel (loaded
//    once) -> zero steady-state weight traffic.
//  - Edge tile staged as f32 via global_load_lds into double-buffered LDS
//    (64 KiB) with SOURCE-side XOR swizzle (dest must be linear); bf16
//    convert at fragment read (cvt_pk). No VGPRs consumed by staging.
//  - Counted s_waitcnt vmcnt(32) once per iter (never drain-to-0);
//    lgkmcnt-only barriers; 2 barriers/iter.
//  - P gathers (Pr/Ps rows, R5 algebra) pipelined 1 tile ahead in regs;
//    indices 2 tiles ahead.
// LDS 96 KiB -> 1 block/CU, 2 waves/SIMD; VGPR ~230.

typedef __attribute__((ext_vector_type(8))) short bf16x8;
typedef __attribute__((ext_vector_type(4))) float f32x4;
typedef __attribute__((ext_vector_type(2))) unsigned int u32x2;

#define NTILE 10000
#define NBLK  256
#define NITER 40          // ceil(NTILE/NBLK); tail tiles wrap (benign dup)

static __device__ __forceinline__ unsigned short f2bf(float f) {
    unsigned u = __builtin_bit_cast(unsigned, f);
    u += 0x7FFFu + ((u >> 16) & 1u);
    return (unsigned short)(u >> 16);
}

static __device__ __forceinline__ unsigned cvt_pk_bf16(float lo, float hi) {
    unsigned r;
    asm("v_cvt_pk_bf16_f32 %0, %1, %2" : "=v"(r) : "v"(lo), "v"(hi));
    return r;
}

static __device__ __forceinline__ float bflo(unsigned u) {
    return __builtin_bit_cast(float, u << 16);
}
static __device__ __forceinline__ float bfhi(unsigned u) {
    return __builtin_bit_cast(float, u & 0xFFFF0000u);
}

static __device__ __forceinline__ void block_sync_lds() {
    __builtin_amdgcn_sched_barrier(0);
    asm volatile("s_waitcnt lgkmcnt(0)" ::: "memory");
    __builtin_amdgcn_s_barrier();
    __builtin_amdgcn_sched_barrier(0);
}

typedef __attribute__((address_space(1))) const unsigned int ga_uint;
typedef __attribute__((address_space(3))) unsigned int lds_uint;

// ---------------- prep kernels (unchanged from R5) ----------------

__global__ void prep_w1_kernel(const float* __restrict__ W1,
                               ushort* __restrict__ w1f) {
    int id = blockIdx.x * 256 + threadIdx.x;
    if (id >= 16 * 12 * 64) return;
    int l = id & 63, blk = id >> 6;
    int ks = blk % 12, gnt = blk / 12;
    int n  = gnt * 16 + (l & 15);
    int k0 = ks * 32 + (l >> 4) * 8;
    ushort tmp[8];
    #pragma unroll
    for (int j = 0; j < 8; ++j) tmp[j] = f2bf(W1[(k0 + j) * 256 + n]);
    *(bf16x8*)&w1f[(size_t)id * 8] = *(bf16x8*)tmp;
}

__global__ void prep_w2_kernel(const float* __restrict__ W2,
                               ushort* __restrict__ w2f) {
    int id = blockIdx.x * 256 + threadIdx.x;
    if (id >= 8 * 8 * 64) return;
    int l = id & 63, blk = id >> 6;
    int ks = blk % 8, gnt = blk / 8;
    int n  = gnt * 16 + (l & 15);
    int k0 = ks * 32 + (l >> 4) * 8;
    ushort tmp[8];
    #pragma unroll
    for (int j = 0; j < 8; ++j) tmp[j] = f2bf(W2[(k0 + j) * 128 + n]);
    *(bf16x8*)&w2f[(size_t)id * 8] = *(bf16x8*)tmp;
}

__global__ void prep_hbias_kernel(const float* __restrict__ W1,
                                  const float* __restrict__ b1,
                                  const float* __restrict__ g,
                                  float* __restrict__ hbias) {
    int n = threadIdx.x;
    float acc = b1[n];
    for (int k = 0; k < 128; ++k) acc += g[k] * W1[(384 + k) * 256 + n];
    hbias[n] = acc;
}

__global__ __launch_bounds__(256) void prep_proj_kernel(
    const float* __restrict__ node_attr,
    const ushort* __restrict__ w1f,
    const float* __restrict__ hbias,
    ushort* __restrict__ Pr,
    ushort* __restrict__ Ps)
{
    __shared__ ushort Xn[64 * 128];

    const int t = threadIdx.x, l = t & 63, wn = t >> 6;
    const int base = blockIdx.x * 64;
    const int lr = l & 15, q = l >> 4, lk = q * 8;

    #pragma unroll
    for (int p = 0; p < 4; ++p) {
        int chunk = p * 256 + t;
        int r  = chunk >> 4;
        int c0 = (chunk & 15) * 8;
        int node = base + r; if (node >= NTILE) node = NTILE - 1;
        const float4* src = (const float4*)(node_attr + (size_t)node * 128 + c0);
        float4 a = src[0];
        float4 b = src[1];
        uint4 uu = { cvt_pk_bf16(a.x, a.y), cvt_pk_bf16(a.z, a.w),
                     cvt_pk_bf16(b.x, b.y), cvt_pk_bf16(b.z, b.w) };
        *(bf16x8*)&Xn[r * 128 + (c0 ^ ((r & 7) << 3))] = __builtin_bit_cast(bf16x8, uu);
    }
    __syncthreads();

    #pragma unroll
    for (int s = 0; s < 2; ++s) {
        f32x4 acc[4][4];
        #pragma unroll
        for (int mt = 0; mt < 4; ++mt)
            #pragma unroll
            for (int nt = 0; nt < 4; ++nt)
                acc[mt][nt] = (f32x4){0.f, 0.f, 0.f, 0.f};

        #pragma unroll
        for (int ks = 0; ks < 4; ++ks) {
            bf16x8 B[4];
            #pragma unroll
            for (int nt = 0; nt < 4; ++nt)
                B[nt] = *(const bf16x8*)&w1f[
                    (size_t)(((wn * 4 + nt) * 12 + 4 + s * 4 + ks) * 64 + l) * 8];
            bf16x8 X[4];
            const int kk = ks * 32 + lk;
            #pragma unroll
            for (int mt = 0; mt < 4; ++mt) {
                const int row = mt * 16 + lr;
                X[mt] = *(const bf16x8*)&Xn[row * 128 + (kk ^ ((row & 7) << 3))];
            }
            #pragma unroll
            for (int mt = 0; mt < 4; ++mt)
                #pragma unroll
                for (int nt = 0; nt < 4; ++nt)
                    acc[mt][nt] = __builtin_amdgcn_mfma_f32_16x16x32_bf16(
                        B[nt], X[mt], acc[mt][nt], 0, 0, 0);
        }

        ushort* P = s ? Ps : Pr;
        #pragma unroll
        for (int nt = 0; nt < 4; ++nt) {
            const int F = wn * 64 + nt * 16 + q * 4;
            float4 hb4 = {0.f, 0.f, 0.f, 0.f};
            if (s == 0) hb4 = *(const float4*)&hbias[F];
            #pragma unroll
            for (int mt = 0; mt < 4; ++mt) {
                const int node = base + mt * 16 + lr;
                if (node < NTILE) {
                    u32x2 w = { cvt_pk_bf16(acc[mt][nt][0] + hb4.x,
                                            acc[mt][nt][1] + hb4.y),
                                cvt_pk_bf16(acc[mt][nt][2] + hb4.z,
                                            acc[mt][nt][3] + hb4.w) };
                    *(u32x2*)&P[(size_t)node * 256 + F] = w;
                }
            }
        }
    }
}

// ---------------- main persistent kernel ----------------

__global__ __launch_bounds__(512, 2) void edge_mlp_kernel(
    const float* __restrict__ edge_attr,   // [E][128] f32
    const int* __restrict__ senders,
    const int* __restrict__ receivers,
    const ushort* __restrict__ w1f,        // frag-packed (ks 0..3 used)
    const ushort* __restrict__ w2f,        // frag-packed
    const ushort* __restrict__ Pr,         // [10000][256] bf16 (has hbias)
    const ushort* __restrict__ Ps,         // [10000][256] bf16
    const float* __restrict__ b2,          // [128]
    float* __restrict__ out)               // [E][128] f32
{
    // Xe: f32 edge tile, double-buffered, LINEAR layout (global_load_lds
    // dest) with source-side XOR swizzle at 16B granule:
    //   LDS[row][slot s] = G[row][s ^ (row&7)]   (32 slots of 16B per row)
    __shared__ float  Xe[2][64 * 128];   // 2 x 32 KiB
    __shared__ ushort Hs[64 * 256];      // 32 KiB, XOR-swizzled (16B granule)

    const int t  = threadIdx.x;
    const int l  = t & 63;
    const int w  = t >> 6;        // wave 0..7
    const int wm = w >> 2;        // 0..1 edge-half
    const int wn = w & 3;         // 0..3 feat-quarter
    const int lr = l & 15;
    const int q  = l >> 4;
    const int b  = blockIdx.x;

    // ---- weights -> registers (held for entire kernel) ----
    bf16x8 W1r[4][4];   // [nt][ks]  : GEMM1, wn's 64 feats, K=128
    #pragma unroll
    for (int nt = 0; nt < 4; ++nt)
        #pragma unroll
        for (int ks = 0; ks < 4; ++ks)
            W1r[nt][ks] = *(const bf16x8*)&w1f[
                (size_t)(((wn * 4 + nt) * 12 + ks) * 64 + l) * 8];
    bf16x8 W2r[2][8];   // [nt2][ks] : GEMM2, wn's 32 feats, K=256
    #pragma unroll
    for (int nt = 0; nt < 2; ++nt)
        #pragma unroll
        for (int ks = 0; ks < 8; ++ks)
            W2r[nt][ks] = *(const bf16x8*)&w2f[
                (size_t)(((wn * 2 + nt) * 8 + ks) * 64 + l) * 8];

    float4 b2v[2];
    #pragma unroll
    for (int nt = 0; nt < 2; ++nt)
        b2v[nt] = *(const float4*)&b2[wn * 32 + nt * 16 + q * 4];

    // ---- pipeline state ----
    int rcA[2], scA[2], rcB[2], scB[2];       // index sets (2-ahead)
    u32x2 pgA[4][2], sgA[4][2], pgB[4][2], sgB[4][2];  // gather sets (1-ahead)

    auto tile_of = [&](int it) {
        int v = b + it * NBLK;
        return v < NTILE ? v : v - NTILE;
    };

    auto stage = [&](int tile, int buf) {
        #pragma unroll
        for (int i = 0; i < 4; ++i) {
            int row = w * 8 + i * 2 + (l >> 5);
            int gs  = (l & 31) ^ (row & 7);
            const unsigned int* src = (const unsigned int*)(edge_attr
                + (size_t)(tile * 64 + row) * 128) + gs * 4;
            unsigned int* dst = (unsigned int*)&Xe[buf][0] + (w * 4 + i) * 256;
            __builtin_amdgcn_global_load_lds((ga_uint*)src, (lds_uint*)dst, 16, 0, 0);
        }
        __builtin_amdgcn_sched_barrier(0);
    };

    auto ld_idx = [&](int tile, int (&rc)[2], int (&sc)[2]) {
        #pragma unroll
        for (int mt = 0; mt < 2; ++mt) {
            int e = tile * 64 + wm * 32 + mt * 16 + lr;
            rc[mt] = receivers[e];
            sc[mt] = senders[e];
        }
        __builtin_amdgcn_sched_barrier(0);
    };

    auto gather = [&](const int (&rc)[2], const int (&sc)[2],
                      u32x2 (&pg)[4][2], u32x2 (&sg)[4][2]) {
        #pragma unroll
        for (int nt = 0; nt < 4; ++nt) {
            const int F = wn * 64 + nt * 16 + q * 4;
            #pragma unroll
            for (int mt = 0; mt < 2; ++mt) {
                pg[nt][mt] = *(const u32x2*)&Pr[(size_t)rc[mt] * 256 + F];
                sg[nt][mt] = *(const u32x2*)&Ps[(size_t)sc[mt] * 256 + F];
            }
        }
        __builtin_amdgcn_sched_barrier(0);
    };

    // ---- prologue ----
    {
        int t0 = tile_of(0), t1 = tile_of(1);
        stage(t0, 0);                 // 4 gload_lds
        ld_idx(t0, rcA, scA);         // 4 loads
        gather(rcA, scA, pgA, sgA);   // 16 loads (tile 0)
        stage(t1, 1);                 // 4 gload_lds
        ld_idx(t1, rcB, scB);         // 4 loads (tile 1 idx)
        // stage(t0) done when <=28 outstanding (16+4+4+4 newer)
        asm volatile("s_waitcnt vmcnt(28)" ::: "memory");
        __builtin_amdgcn_sched_barrier(0);
        __builtin_amdgcn_s_barrier();
        __builtin_amdgcn_sched_barrier(0);
    }

    // ---- main loop: body(it) with static parity (buf = it&1) ----
    auto body = [&](int it, int buf,
                    int (&rcUse)[2], int (&scUse)[2],       // idx(t+1)
                    int (&rcLoad)[2], int (&scLoad)[2],     // <- idx(t+2)
                    u32x2 (&pgC)[4][2], u32x2 (&sgC)[4][2], // gathers(t) in flight
                    u32x2 (&pgN)[4][2], u32x2 (&sgN)[4][2]) // <- gathers(t+1)
    {
        const int tc = tile_of(it);

        // 1. indices for t+2
        ld_idx(tile_of(it + 2), rcLoad, scLoad);

        // 2. GEMM1: K=128 from Xe[buf] (f32, swizzled slots, cvt at read)
        f32x4 acc[2][4];
        #pragma unroll
        for (int mt = 0; mt < 2; ++mt)
            #pragma unroll
            for (int nt = 0; nt < 4; ++nt)
                acc[mt][nt] = (f32x4){0.f, 0.f, 0.f, 0.f};

        #pragma unroll
        for (int ks = 0; ks < 4; ++ks) {
            bf16x8 X[2];
            #pragma unroll
            for (int mt = 0; mt < 2; ++mt) {
                const int edge = wm * 32 + mt * 16 + lr;
                const int s0 = ks * 8 + q * 2;
                const char* base = (const char*)&Xe[buf][0] + edge * 512;
                float4 xa = *(const float4*)(base + (((s0)     ^ (edge & 7)) * 16));
                float4 xb = *(const float4*)(base + (((s0 + 1) ^ (edge & 7)) * 16));
                uint4 uu = { cvt_pk_bf16(xa.x, xa.y), cvt_pk_bf16(xa.z, xa.w),
                             cvt_pk_bf16(xb.x, xb.y), cvt_pk_bf16(xb.z, xb.w) };
                X[mt] = __builtin_bit_cast(bf16x8, uu);
            }
            #pragma unroll
            for (int mt = 0; mt < 2; ++mt)
                #pragma unroll
                for (int nt = 0; nt < 4; ++nt)
                    acc[mt][nt] = __builtin_amdgcn_mfma_f32_16x16x32_bf16(
                        W1r[nt][ks], X[mt], acc[mt][nt], 0, 0, 0);
        }

        // 3. epilogue 1: + Pr + Ps, relu, cvt_pk -> 8B swizzled Hs writes
        #pragma unroll
        for (int nt = 0; nt < 4; ++nt) {
            const int F = wn * 64 + nt * 16 + q * 4;
            #pragma unroll
            for (int mt = 0; mt < 2; ++mt) {
                u32x2 p = pgC[nt][mt], s = sgC[nt][mt];
                float v0 = fmaxf(acc[mt][nt][0] + bflo(p.x) + bflo(s.x), 0.f);
                float v1 = fmaxf(acc[mt][nt][1] + bfhi(p.x) + bfhi(s.x), 0.f);
                float v2 = fmaxf(acc[mt][nt][2] + bflo(p.y) + bflo(s.y), 0.f);
                float v3 = fmaxf(acc[mt][nt][3] + bfhi(p.y) + bfhi(s.y), 0.f);
                u32x2 wv = { cvt_pk_bf16(v0, v1), cvt_pk_bf16(v2, v3) };
                const int edge = wm * 32 + mt * 16 + lr;
                *(u32x2*)&Hs[edge * 256 + (F ^ ((edge & 7) << 3))] = wv;
            }
        }

        // 4. gathers for t+1 (resolve under GEMM2 + next GEMM1)
        gather(rcUse, scUse, pgN, sgN);

        // 5. Hs ready + all waves done reading Xe[buf]
        block_sync_lds();

        // 6. stage t+2 into Xe[buf] (consumed 2 iters later)
        stage(tile_of(it + 2), buf);

        // 7. GEMM2: K=256 from Hs, W2 in regs; epilogue stores
        f32x4 acc2[2][2];
        #pragma unroll
        for (int mt = 0; mt < 2; ++mt)
            #pragma unroll
            for (int nt = 0; nt < 2; ++nt)
                acc2[mt][nt] = (f32x4){0.f, 0.f, 0.f, 0.f};

        #pragma unroll
        for (int ks = 0; ks < 8; ++ks) {
            bf16x8 Hfr[2];
            #pragma unroll
            for (int mt = 0; mt < 2; ++mt) {
                const int edge = wm * 32 + mt * 16 + lr;
                const int F0 = ks * 32 + q * 8;
                Hfr[mt] = *(const bf16x8*)&Hs[edge * 256 + (F0 ^ ((edge & 7) << 3))];
            }
            #pragma unroll
            for (int mt = 0; mt < 2; ++mt)
                #pragma unroll
                for (int nt = 0; nt < 2; ++nt)
                    acc2[mt][nt] = __builtin_amdgcn_mfma_f32_16x16x32_bf16(
                        W2r[nt][ks], Hfr[mt], acc2[mt][nt], 0, 0, 0);
        }

        #pragma unroll
        for (int nt = 0; nt < 2; ++nt) {
            const int F = wn * 32 + nt * 16 + q * 4;
            #pragma unroll
            for (int mt = 0; mt < 2; ++mt) {
                const int e = tc * 64 + wm * 32 + mt * 16 + lr;
                float4 o = { acc2[mt][nt][0] + b2v[nt].x, acc2[mt][nt][1] + b2v[nt].y,
                             acc2[mt][nt][2] + b2v[nt].z, acc2[mt][nt][3] + b2v[nt].w };
                *(float4*)&out[(size_t)e * 128 + F] = o;
            }
        }
        __builtin_amdgcn_sched_barrier(0);

        // 8. ensure stage(t+1) complete (it has 32 newer VMEM ops:
        //    prev stores 4 + idx 4 + gathers 16 + stage(t+2) 4 + stores 4)
        asm volatile("s_waitcnt vmcnt(32)" ::: "memory");
        __builtin_amdgcn_sched_barrier(0);
        __builtin_amdgcn_s_barrier();
        __builtin_amdgcn_sched_barrier(0);
    };

    #pragma unroll 1
    for (int it = 0; it < NITER; it += 2) {
        body(it,     0, rcB, scB, rcA, scA, pgA, sgA, pgB, sgB);
        body(it + 1, 1, rcA, scA, rcB, scB, pgB, sgB, pgA, sgA);
    }
}

// ---------------- launcher ----------------

extern "C" void kernel_launch(void* const* d_in, const int* in_sizes, int n_in,
                              void* d_out, int out_size, void* d_ws, size_t ws_size,
                              hipStream_t stream) {
    (void)in_sizes; (void)n_in; (void)out_size; (void)ws_size;

    const float* edge_attr   = (const float*)d_in[0];
    const float* node_attr   = (const float*)d_in[1];
    const float* global_attr = (const float*)d_in[2];
    const int*   senders     = (const int*)d_in[3];
    const int*   receivers   = (const int*)d_in[4];
    const float* W1          = (const float*)d_in[5];
    const float* b1          = (const float*)d_in[6];
    const float* W2          = (const float*)d_in[7];
    const float* b2          = (const float*)d_in[8];
    float* out = (float*)d_out;

    ushort* w1f   = (ushort*)d_ws;                          //   196,608 B
    ushort* w2f   = (ushort*)((char*)d_ws + 196608);        //    65,536 B
    float*  hbias = (float*)((char*)d_ws + 262144);         //     1,024 B
    ushort* Pr    = (ushort*)((char*)d_ws + 263168);        // 5,120,000 B
    ushort* Ps    = (ushort*)((char*)d_ws + 5383168);       // 5,120,000 B

    hipLaunchKernelGGL(prep_w1_kernel,    dim3(48),  dim3(256), 0, stream, W1, w1f);
    hipLaunchKernelGGL(prep_w2_kernel,    dim3(16),  dim3(256), 0, stream, W2, w2f);
    hipLaunchKernelGGL(prep_hbias_kernel, dim3(1),   dim3(256), 0, stream, W1, b1, global_attr, hbias);
    hipLaunchKernelGGL(prep_proj_kernel,  dim3(157), dim3(256), 0, stream,
                       node_attr, w1f, hbias, Pr, Ps);

    hipLaunchKernelGGL(edge_mlp_kernel, dim3(NBLK), dim3(512), 0, stream,
                       edge_attr, senders, receivers, w1f, w2f, Pr, Ps, b2, out);
}